// Round 10
// baseline (560.903 us; speedup 1.0000x reference)
//
#include <hip/hip_runtime.h>

#define S_LEN 2048
#define D_DIM 64
#define BM    128
#define BN    64
#define NT    512          // 4 compute waves + 4 producer waves
#define BH    64           // B*H
#define QB    (S_LEN / BM) // 16 query blocks per head

typedef __attribute__((ext_vector_type(4)))  _Float16 half4;
typedef __attribute__((ext_vector_type(8)))  _Float16 half8;
typedef __attribute__((ext_vector_type(16))) float    f32x16;

#define MFMA3216(a, b, c) __builtin_amdgcn_mfma_f32_32x32x16_f16((a), (b), (c), 0, 0, 0)

// v_mfma_f32_32x32x16_f16 layouts (gfx950 2xK family):
//   A[m][k]: m = lane&31, k = 8*(lane>>5) + e
//   B[k][n]: n = lane&31, k = 8*(lane>>5) + e
//   C[row][col]: col = lane&31, row = (e&3) + 8*(e>>2) + 4*(lane>>5)  [m101]
// S^T = K.Q^T -> lane holds 32 keys of ONE query. No max-subtraction softmax.
// O accumulates untouched in AGPRs; single divide by l at the end.
//
// R10 = R9 resubmitted byte-identical (R9's bench was an infra failure:
// "container failed twice", no compile/correctness/timing verdict; barrier
// parity across the role branches re-audited: 1+nTiles each, wave-aligned
// divergence only -> no hang path).
//
// R9 = R8 (balanced qb mapping, dbuf LDS, 1 barrier/tile) + producer/consumer
// wave specialization:
//   threads 0-255   = 4 compute waves (no staging -> no vmcnt stall in path)
//   threads 256-511 = 4 producer waves (loads + cvt + LDS writes only)
// LDS unchanged 34816B -> still 4 blocks/CU, but now 32 waves/CU (was 16):
// producer stalls hide under consumer compute on the same SIMD.
// __launch_bounds__(512,8) pins VGPR<=64 so 8 waves/SIMD actually fit.
// Barrier counts match per role: 1 prologue + nTiles in-loop each.

__global__ __launch_bounds__(NT, 8) void fa_fwd(const float* __restrict__ Q,
                                                const float* __restrict__ K,
                                                const float* __restrict__ V,
                                                float* __restrict__ Out) {
  // K tile [key][d]: 64 -> 68 halfs/row (136B = 8B-aligned; 2-way banks free)
  __shared__ _Float16 kh[2][BN][68];
  // V^T tile [d][pos], pos = permuted key 0..63: 68 halfs/row
  __shared__ _Float16 vT[2][D_DIM][68];

  const int tid = threadIdx.x;

  // ---- balanced work mapping (R8): per-CU qb = {15-a, a, 11-a, 4+a} ----
  const int bid = blockIdx.x;
  const int c   = bid & 255;
  const int g   = bid >> 8;   // 0..3
  const int a   = c >> 6;     // 0..3
  const int bh  = c & 63;
  const int qb  = (g & 1) ? (2 * (g - 1) + a) : (15 - 2 * g - a);
  const int q0  = qb * BM;
  const long base = (long)bh * S_LEN * D_DIM;
  const int nTiles = 2 * (qb + 1); // even, >= 2

  const float SCALE = 0.125f * 1.44269504088896340736f; // 1/sqrt(64)*log2(e)

  union H8 { half4 q[2]; half8 o; };

  if (tid < 256) {
    // ================= CONSUMER: 4 compute waves =================
    const int wave = tid >> 6;
    const int lane = tid & 63;
    const int h    = lane >> 5;
    const int qc   = lane & 31;
    const int q0w  = q0 + wave * 32;
    const int myEnd = q0w + 31;

    // Q^T fragments (B-operand), once: qf[cc][e] = Q[d = 16cc + 8h + e]
    half8 qf[4];
    {
      const float* qp = Q + base + (long)(q0w + qc) * D_DIM;
#pragma unroll
      for (int cc = 0; cc < 4; ++cc) {
        float4 u = *(const float4*)(qp + 16 * cc + 8 * h);
        float4 v = *(const float4*)(qp + 16 * cc + 8 * h + 4);
        half8 t;
        t[0] = (_Float16)(u.x * SCALE); t[1] = (_Float16)(u.y * SCALE);
        t[2] = (_Float16)(u.z * SCALE); t[3] = (_Float16)(u.w * SCALE);
        t[4] = (_Float16)(v.x * SCALE); t[5] = (_Float16)(v.y * SCALE);
        t[6] = (_Float16)(v.z * SCALE); t[7] = (_Float16)(v.w * SCALE);
        qf[cc] = t;
      }
    }

    f32x16 o0, o1;
#pragma unroll
    for (int e = 0; e < 16; ++e) { o0[e] = 0.f; o1[e] = 0.f; }
    float l = 0.f;

    __syncthreads(); // matches producer prologue barrier (tile 0 staged)

    for (int t = 0; t < nTiles; ++t) {
      const int n0  = t * BN;
      const int cur = t & 1;
      if (n0 <= myEnd) {
        const _Float16 (*khc)[68] = kh[cur];
        const _Float16 (*vTc)[68] = vT[cur];
#pragma unroll
        for (int s = 0; s < 2; ++s) {
          const int sbase = n0 + 32 * s;
          if (sbase > myEnd) break;

          // S^T = K . Q^T (4 chunks of K=16 over d)
          f32x16 st;
#pragma unroll
          for (int e = 0; e < 16; ++e) st[e] = 0.f;
#pragma unroll
          for (int cc = 0; cc < 4; ++cc) {
            H8 kf;
            kf.q[0] = *(const half4*)&khc[32 * s + qc][16 * cc + 8 * h];
            kf.q[1] = *(const half4*)&khc[32 * s + qc][16 * cc + 8 * h + 4];
            st = MFMA3216(kf.o, qf[cc], st);
          }

          // causal mask (diagonal subtiles only)
          if (sbase + 31 > q0w) {
#pragma unroll
            for (int e = 0; e < 16; ++e) {
              int key = sbase + (e & 3) + 8 * (e >> 2) + 4 * h;
              if (key > q0w + qc) st[e] = -1e30f;
            }
          }

          // p = exp2(s), tree-sum l
#pragma unroll
          for (int e = 0; e < 16; ++e) st[e] = __builtin_amdgcn_exp2f(st[e]);
          {
            float t0 = (st[0] + st[1])   + (st[2] + st[3]);
            float t1 = (st[4] + st[5])   + (st[6] + st[7]);
            float t2 = (st[8] + st[9])   + (st[10] + st[11]);
            float t3 = (st[12] + st[13]) + (st[14] + st[15]);
            l += (t0 + t1) + (t2 + t3);
          }

          // O^T += V^T . P^T, P^T straight from C regs
#pragma unroll
          for (int cl = 0; cl < 2; ++cl) {
            half8 pf;
#pragma unroll
            for (int j = 0; j < 8; ++j) pf[j] = (_Float16)st[8 * cl + j];
            const int cg = 2 * s + cl;
            H8 v0, v1;
            v0.q[0] = *(const half4*)&vTc[qc][16 * cg + 8 * h];
            v0.q[1] = *(const half4*)&vTc[qc][16 * cg + 8 * h + 4];
            v1.q[0] = *(const half4*)&vTc[32 + qc][16 * cg + 8 * h];
            v1.q[1] = *(const half4*)&vTc[32 + qc][16 * cg + 8 * h + 4];
            o0 = MFMA3216(v0.o, pf, o0);
            o1 = MFMA3216(v1.o, pf, o1);
          }
        }
      }
      __syncthreads();
    }

    // epilogue: combine halves' l, divide, store
    l += __shfl_xor(l, 32);
    const float invl = 1.0f / l;
    float* op = Out + base + (long)(q0w + qc) * D_DIM;
#pragma unroll
    for (int e = 0; e < 16; ++e) {
      int d = (e & 3) + 8 * (e >> 2) + 4 * h;
      op[d]      = o0[e] * invl;
      op[32 + d] = o1[e] * invl;
    }
  } else {
    // ================= PRODUCER: 4 staging waves =================
    const int ptid = tid - 256;
    const int skey = ptid >> 2, sc = (ptid & 3) * 16; // K: 64B fp32 per thread
    const int sd   = ptid & 63, sr = ptid >> 6;       // V: 16 keys at one d
    const float* kstage = K + base + (long)skey * D_DIM + sc;
    const float* vstage = V + base + (long)(16 * sr) * D_DIM + sd;

    float kreg[16], vreg[16];

#define PLOAD(T)                                                             \
    {                                                                        \
      const float* kp = kstage + (long)(T) * BN * D_DIM;                     \
      const float* vp = vstage + (long)(T) * BN * D_DIM;                     \
      _Pragma("unroll")                                                      \
      for (int j = 0; j < 4; ++j)                                            \
        *(float4*)&kreg[4 * j] = *(const float4*)(kp + 4 * j);               \
      _Pragma("unroll")                                                      \
      for (int j = 0; j < 16; ++j) vreg[j] = vp[(long)j * D_DIM];            \
    }

#define PWRITE(B)                                                            \
    {                                                                        \
      _Pragma("unroll")                                                      \
      for (int j = 0; j < 4; ++j) {                                          \
        half4 tk;                                                            \
        tk[0] = (_Float16)kreg[4 * j];     tk[1] = (_Float16)kreg[4 * j + 1];\
        tk[2] = (_Float16)kreg[4 * j + 2]; tk[3] = (_Float16)kreg[4 * j + 3];\
        *(half4*)&kh[B][skey][sc + 4 * j] = tk;                              \
      }                                                                      \
      _Pragma("unroll")                                                      \
      for (int p = 0; p < 4; ++p) {                                          \
        constexpr int inv[4] = {0, 2, 1, 3}; /* quad-swap key perm */        \
        half4 tv4;                                                           \
        _Pragma("unroll")                                                    \
        for (int j = 0; j < 4; ++j) tv4[j] = (_Float16)vreg[inv[p] * 4 + j]; \
        *(half4*)&vT[B][sd][16 * sr + 4 * p] = tv4;                          \
      }                                                                      \
    }

    // prologue: stage tile 0 into buffer 0
    PLOAD(0);
    PWRITE(0);
    __syncthreads();

    for (int t = 0; t < nTiles; ++t) {
      if (t + 1 < nTiles) {
        PLOAD(t + 1);
        PWRITE((t + 1) & 1); // stall on vmcnt here is hidden by consumer waves
      }
      __syncthreads();
    }
#undef PLOAD
#undef PWRITE
  }
}

extern "C" void kernel_launch(void* const* d_in, const int* in_sizes, int n_in,
                              void* d_out, int out_size, void* d_ws, size_t ws_size,
                              hipStream_t stream) {
  const float* Q = (const float*)d_in[0];
  const float* K = (const float*)d_in[1];
  const float* V = (const float*)d_in[2];
  (void)in_sizes; (void)n_in; (void)d_ws; (void)ws_size; (void)out_size;
  float* Out = (float*)d_out;
  dim3 grid(BH * QB); // 1024 blocks
  dim3 block(NT);     // 512 threads (4 compute + 4 producer waves)
  hipLaunchKernelGGL(fa_fwd, grid, block, 0, stream, Q, K, V, Out);
}

// Round 11
// 544.052 us; speedup vs baseline: 1.0310x; 1.0310x over previous
//
#include <hip/hip_runtime.h>

#define S_LEN 2048
#define D_DIM 64
#define BM    128
#define BN    64
#define NW    4            // waves per block
#define NT    (NW * 64)    // 256 threads
#define BH    64           // B*H
#define QB    (S_LEN / BM) // 16 query blocks per head

// split-K workspace: qb>=8 q-blocks split into 2 key-halves
#define NSPLIT        512                      // 8 qb values x 64 heads
#define WS_OB_FLOATS  (NSPLIT * 128 * 64)      // halfB o partials
#define WS_L_FLOATS   (NSPLIT * 256)           // l partials (2 halves x 128 rows)
#define WS_CNT_OFF    ((WS_OB_FLOATS + WS_L_FLOATS) * 4)
#define WS_NEED       (WS_CNT_OFF + NSPLIT * 4)

typedef __attribute__((ext_vector_type(4)))  _Float16 half4;
typedef __attribute__((ext_vector_type(8)))  _Float16 half8;
typedef __attribute__((ext_vector_type(16))) float    f32x16;

#define MFMA3216(a, b, c) __builtin_amdgcn_mfma_f32_32x32x16_f16((a), (b), (c), 0, 0, 0)

// R11 = R8's proven inner loop (dbuf LDS, loads-at-top/write-after-compute,
// one __syncthreads per tile) + split-K work decomposition:
//  - R10 post-mortem: launch_bounds(512,8) forced 64 regs -> spilled acc to
//    scratch (FETCH 812GB, 458us). Specialization abandoned; conservation:
//    q-row-owning waves = 4096 = 16/CU cap. Past that only via split-K.
//  - R8's residual stall = concurrency decay: co-resident blocks {32,2,24,10}
//    tiles retire at different times; last iters run 1 block/CU (occ 28%).
//  - Fix: qb>=8 split into 2 key-halves (<=16 tiles each); 1536 items sorted
//    length-desc -> 1024 resident + 512 LPT backfill, concurrency ~4 held.
//  - Combine uses no-max-softmax additivity: O=(oA+oB)/(lA+lB). halfA->Out,
//    halfB->ws, l->ws (agent-scope stores); per-sid counter; last block
//    combines. No spin. Counters memset (2KB) per launch, capture-safe.
//  - ws_size gate: < WS_NEED -> launch the unmodified R8 kernel.

// item tables: 24 items/head, sorted by tile-length desc
static __device__ const signed char ITEM_QB[24] =
  {15,15, 7,14,14,13,13, 6,12,12,11,11, 5,10,10, 9, 9, 4, 8, 8, 3, 2, 1, 0};
static __device__ const signed char ITEM_T0[24] =
  { 0,16, 0, 0,15, 0,14, 0, 0,13, 0,12, 0, 0,11, 0,10, 0, 0, 9, 0, 0, 0, 0};
static __device__ const signed char ITEM_T1[24] =
  {16,32,16,15,30,14,28,14,13,26,12,24,12,11,22,10,20,10, 9,18, 8, 6, 4, 2};

static __device__ __forceinline__ void ast(float* p, float v) {
  __hip_atomic_store(p, v, __ATOMIC_RELAXED, __HIP_MEMORY_SCOPE_AGENT);
}
static __device__ __forceinline__ float ald(const float* p) {
  return __hip_atomic_load(p, __ATOMIC_RELAXED, __HIP_MEMORY_SCOPE_AGENT);
}

template <bool SPLIT>
__global__ __launch_bounds__(NT, 4) void fa_fwd(const float* __restrict__ Q,
                                                const float* __restrict__ K,
                                                const float* __restrict__ V,
                                                float* __restrict__ Out,
                                                float* __restrict__ wsF,
                                                int* __restrict__ wsCnt) {
  __shared__ _Float16 kh[2][BN][68];
  __shared__ _Float16 vT[2][D_DIM][68];
  __shared__ int lastFlag;

  const int tid  = threadIdx.x;
  const int wave = tid >> 6;
  const int lane = tid & 63;
  const int h    = lane >> 5;
  const int qc   = lane & 31;

  int bh, qb, t0, t1, sid = 0;
  bool isSplit = false, halfB = false;
  if constexpr (SPLIT) {
    const int item = blockIdx.x >> 6;
    bh = blockIdx.x & 63;
    qb = ITEM_QB[item]; t0 = ITEM_T0[item]; t1 = ITEM_T1[item];
    isSplit = (qb >= 8);
    halfB   = (t0 != 0);
    sid     = (qb - 8) * 64 + bh;
  } else {
    // R8 balanced mapping (fallback)
    const int c = blockIdx.x & 255, g = blockIdx.x >> 8, a = c >> 6;
    bh = c & 63;
    qb = (g & 1) ? (2 * (g - 1) + a) : (15 - 2 * g - a);
    t0 = 0; t1 = 2 * (qb + 1);
  }
  const int q0  = qb * BM;
  const int q0w = q0 + wave * 32;
  const long base = (long)bh * S_LEN * D_DIM;

  const float SCALE = 0.125f * 1.44269504088896340736f; // 1/sqrt(64)*log2(e)

  // ---- Q^T fragments (B-operand), once ----
  half8 qf[4];
  {
    const float* qp = Q + base + (long)(q0w + qc) * D_DIM;
#pragma unroll
    for (int cc = 0; cc < 4; ++cc) {
      float4 u = *(const float4*)(qp + 16 * cc + 8 * h);
      float4 v = *(const float4*)(qp + 16 * cc + 8 * h + 4);
      half8 t;
      t[0] = (_Float16)(u.x * SCALE); t[1] = (_Float16)(u.y * SCALE);
      t[2] = (_Float16)(u.z * SCALE); t[3] = (_Float16)(u.w * SCALE);
      t[4] = (_Float16)(v.x * SCALE); t[5] = (_Float16)(v.y * SCALE);
      t[6] = (_Float16)(v.z * SCALE); t[7] = (_Float16)(v.w * SCALE);
      qf[cc] = t;
    }
  }

  f32x16 o0, o1;
#pragma unroll
  for (int e = 0; e < 16; ++e) { o0[e] = 0.f; o1[e] = 0.f; }
  float l = 0.f;

  const int myEnd = q0w + 31;

  // staging roles (256 threads)
  const int skey = tid >> 2, sc = (tid & 3) * 16;
  const int sd   = tid & 63, sr = tid >> 6;
  const float* kstage = K + base + (long)skey * D_DIM + sc;
  const float* vstage = V + base + (long)(16 * sr) * D_DIM + sd;

  union H8 { half4 q[2]; half8 o; };

  float kreg[16], vreg[16];

  // ---- prologue: stage tile t0 into buffer t0&1 ----
  {
    const float* kp = kstage + (long)t0 * BN * D_DIM;
    const float* vp = vstage + (long)t0 * BN * D_DIM;
#pragma unroll
    for (int j = 0; j < 4; ++j)
      *(float4*)&kreg[4 * j] = *(const float4*)(kp + 4 * j);
#pragma unroll
    for (int j = 0; j < 16; ++j) vreg[j] = vp[(long)j * D_DIM];
    const int b0 = t0 & 1;
#pragma unroll
    for (int j = 0; j < 4; ++j) {
      half4 t;
      t[0] = (_Float16)kreg[4 * j];     t[1] = (_Float16)kreg[4 * j + 1];
      t[2] = (_Float16)kreg[4 * j + 2]; t[3] = (_Float16)kreg[4 * j + 3];
      *(half4*)&kh[b0][skey][sc + 4 * j] = t;
    }
#pragma unroll
    for (int p = 0; p < 4; ++p) {
      constexpr int inv[4] = {0, 2, 1, 3};
      half4 t;
#pragma unroll
      for (int j = 0; j < 4; ++j) t[j] = (_Float16)vreg[inv[p] * 4 + j];
      *(half4*)&vT[b0][sd][16 * sr + 4 * p] = t;
    }
  }
  __syncthreads();

  for (int t = t0; t < t1; ++t) {
    const int n0   = t * BN;
    const int cur  = t & 1;
    const bool more = (t + 1 < t1);

    if (more) {
      const float* kp = kstage + (long)(t + 1) * BN * D_DIM;
      const float* vp = vstage + (long)(t + 1) * BN * D_DIM;
#pragma unroll
      for (int j = 0; j < 4; ++j)
        *(float4*)&kreg[4 * j] = *(const float4*)(kp + 4 * j);
#pragma unroll
      for (int j = 0; j < 16; ++j) vreg[j] = vp[(long)j * D_DIM];
    }

    if (n0 <= myEnd) {
      const _Float16 (*khc)[68] = kh[cur];
      const _Float16 (*vTc)[68] = vT[cur];
#pragma unroll
      for (int s = 0; s < 2; ++s) {
        const int sbase = n0 + 32 * s;
        if (sbase > myEnd) break;

        f32x16 st;
#pragma unroll
        for (int e = 0; e < 16; ++e) st[e] = 0.f;
#pragma unroll
        for (int cc = 0; cc < 4; ++cc) {
          H8 kf;
          kf.q[0] = *(const half4*)&khc[32 * s + qc][16 * cc + 8 * h];
          kf.q[1] = *(const half4*)&khc[32 * s + qc][16 * cc + 8 * h + 4];
          st = MFMA3216(kf.o, qf[cc], st);
        }

        if (sbase + 31 > q0w) {
#pragma unroll
          for (int e = 0; e < 16; ++e) {
            int key = sbase + (e & 3) + 8 * (e >> 2) + 4 * h;
            if (key > q0w + qc) st[e] = -1e30f;
          }
        }

#pragma unroll
        for (int e = 0; e < 16; ++e) st[e] = __builtin_amdgcn_exp2f(st[e]);
        {
          float u0 = (st[0] + st[1])   + (st[2] + st[3]);
          float u1 = (st[4] + st[5])   + (st[6] + st[7]);
          float u2 = (st[8] + st[9])   + (st[10] + st[11]);
          float u3 = (st[12] + st[13]) + (st[14] + st[15]);
          l += (u0 + u1) + (u2 + u3);
        }

#pragma unroll
        for (int cl = 0; cl < 2; ++cl) {
          half8 pf;
#pragma unroll
          for (int j = 0; j < 8; ++j) pf[j] = (_Float16)st[8 * cl + j];
          const int cg = 2 * s + cl;
          H8 v0, v1;
          v0.q[0] = *(const half4*)&vTc[qc][16 * cg + 8 * h];
          v0.q[1] = *(const half4*)&vTc[qc][16 * cg + 8 * h + 4];
          v1.q[0] = *(const half4*)&vTc[32 + qc][16 * cg + 8 * h];
          v1.q[1] = *(const half4*)&vTc[32 + qc][16 * cg + 8 * h + 4];
          o0 = MFMA3216(v0.o, pf, o0);
          o1 = MFMA3216(v1.o, pf, o1);
        }
      }
    }

    if (more) {
      const int nb = (t + 1) & 1;
#pragma unroll
      for (int j = 0; j < 4; ++j) {
        half4 t2;
        t2[0] = (_Float16)kreg[4 * j];     t2[1] = (_Float16)kreg[4 * j + 1];
        t2[2] = (_Float16)kreg[4 * j + 2]; t2[3] = (_Float16)kreg[4 * j + 3];
        *(half4*)&kh[nb][skey][sc + 4 * j] = t2;
      }
#pragma unroll
      for (int p = 0; p < 4; ++p) {
        constexpr int inv[4] = {0, 2, 1, 3};
        half4 t2;
#pragma unroll
        for (int j = 0; j < 4; ++j) t2[j] = (_Float16)vreg[inv[p] * 4 + j];
        *(half4*)&vT[nb][sd][16 * sr + 4 * p] = t2;
      }
    }
    __syncthreads();
  }

  // ---- epilogue ----
  l += __shfl_xor(l, 32); // full-row l for THIS block's key range

  if (!isSplit) {
    const float invl = 1.0f / l;
    float* op = Out + base + (long)(q0w + qc) * D_DIM;
#pragma unroll
    for (int e = 0; e < 16; ++e) {
      int d = (e & 3) + 8 * (e >> 2) + 4 * h;
      op[d]      = o0[e] * invl;
      op[32 + d] = o1[e] * invl;
    }
  } else {
    // split: publish partials (halfA -> Out, halfB -> ws), l -> ws
    const int lrow = wave * 32 + qc; // 0..127 within q-block
    float* obase = halfB ? (wsF + (long)sid * 8192)
                         : (Out + base + (long)q0 * D_DIM);
    float* lbase = wsF + WS_OB_FLOATS + (long)sid * 256 + (halfB ? 128 : 0);
#pragma unroll
    for (int e = 0; e < 16; ++e) {
      int d = (e & 3) + 8 * (e >> 2) + 4 * h;
      ast(&obase[(long)lrow * 64 + d],      o0[e]);
      ast(&obase[(long)lrow * 64 + d + 32], o1[e]);
    }
    if (h == 0) ast(&lbase[lrow], l);
    __threadfence();
    __syncthreads();
    if (tid == 0) {
      lastFlag = __hip_atomic_fetch_add(&wsCnt[sid], 1, __ATOMIC_ACQ_REL,
                                        __HIP_MEMORY_SCOPE_AGENT);
    }
    __syncthreads();
    if (lastFlag == 1) {
      // last arriver: combine both partials, divide, final store
      float* op = Out + base + (long)q0 * D_DIM;
      const float* ob = wsF + (long)sid * 8192;
      const float* lb = wsF + WS_OB_FLOATS + (long)sid * 256;
      const float lT  = ald(&lb[lrow]) + ald(&lb[128 + lrow]);
      const float invl = 1.0f / lT;
#pragma unroll
      for (int e = 0; e < 16; ++e) {
        int d = (e & 3) + 8 * (e >> 2) + 4 * h;
        long i0 = (long)lrow * 64 + d;
        long i1 = i0 + 32;
        op[i0] = (ald(&op[i0]) + ald(&ob[i0])) * invl;
        op[i1] = (ald(&op[i1]) + ald(&ob[i1])) * invl;
      }
    }
  }
}

extern "C" void kernel_launch(void* const* d_in, const int* in_sizes, int n_in,
                              void* d_out, int out_size, void* d_ws, size_t ws_size,
                              hipStream_t stream) {
  const float* Q = (const float*)d_in[0];
  const float* K = (const float*)d_in[1];
  const float* V = (const float*)d_in[2];
  (void)in_sizes; (void)n_in; (void)out_size;
  float* Out = (float*)d_out;
  if (d_ws != nullptr && ws_size >= (size_t)WS_NEED) {
    float* wsF  = (float*)d_ws;
    int*   wsCnt = (int*)((char*)d_ws + WS_CNT_OFF);
    hipMemsetAsync(wsCnt, 0, NSPLIT * 4, stream); // capture-safe, 2KB
    hipLaunchKernelGGL(HIP_KERNEL_NAME(fa_fwd<true>), dim3(24 * BH), dim3(NT),
                       0, stream, Q, K, V, Out, wsF, wsCnt);
  } else {
    hipLaunchKernelGGL(HIP_KERNEL_NAME(fa_fwd<false>), dim3(BH * QB), dim3(NT),
                       0, stream, Q, K, V, Out, (float*)d_ws, (int*)d_ws);
  }
}